// Round 8
// baseline (26.776 us; speedup 1.0000x reference)
//
#include <hip/hip_runtime.h>
#include <hip/hip_bf16.h>

// x: [32768, 3, 16, 16] f32 ; lhs: [2, 16, 8] ; rhs: [2, 8, 16] ; W: [1, 3072] ; b: [1]
// out: [32768] f32
//
// Algebraic collapse (verified R1-R7, absmax <= 1e-3):
//   out[b] = dot(x[b] (768 f32), Weff (768 f32)) + bias
//   Weff[ch, r*8+p, c*8+q] = sum_{P,Q} lhs[r,P,p] * rhs[c,q,Q]
//                            * W[ch*1024 + (r*16+P)*32 + (c*16+Q)]
//
// R8: producer-consumer wave specialization, NO mid-kernel s_barrier
// (hipcc drains vmcnt(0) at every s_barrier -> R6/R7's exposed bubble).
// Wave 0: params -> LDS via global_load_lds, computes weff alone (the
// j-preserving lane mapping makes tmp lane-private), fence, LDS flag.
// Waves 1-3: issue x loads, spin on flag (lgkmcnt only - x stays in
// flight), then the R7 depth-2 barrier-free streaming loop. The only
// __syncthreads is at the top with nothing outstanding (free).

#define BATCH 32768
#define ROW_F4 192              // 768 floats per sample in float4 units
#define ROWS_PER_BLOCK 32
#define GRID_BLOCKS (BATCH / ROWS_PER_BLOCK)   // 1024 = 4 blocks/CU, 1 generation

// LDS float offsets for the param block
#define PRM_W    0
#define PRM_RHS  3072
#define PRM_LHS  3328
#define PRM_TOT  3584

__device__ __forceinline__ float dot4(const float4& a, const float4& b) {
    return a.x * b.x + a.y * b.y + a.z * b.z + a.w * b.w;
}

// async 16B/lane global->LDS (wave-uniform LDS base + lane*16)
__device__ __forceinline__ void async_lds16(const float* g, float* l) {
    __builtin_amdgcn_global_load_lds(
        (const __attribute__((address_space(1))) unsigned int*)g,
        (__attribute__((address_space(3))) unsigned int*)l, 16, 0, 0);
}

// Merged 2-row wave64 reduction: 6 shfl; lanes 0/1 store rows 0/1.
__device__ __forceinline__ void reduce2_store(float a0, float a1, int lane,
                                              float* __restrict__ outp,
                                              float bias) {
    a0 += __shfl_xor(a0, 1);
    a1 += __shfl_xor(a1, 1);
    float b = (lane & 1) ? a1 : a0;
    b += __shfl_xor(b, 2);
    b += __shfl_xor(b, 4);
    b += __shfl_xor(b, 8);
    b += __shfl_xor(b, 16);
    b += __shfl_xor(b, 32);
    if (lane < 2) outp[lane] = b + bias;
}

__global__ __launch_bounds__(256, 4) void fused_pc_kernel(
        const float4* __restrict__ x4,
        const float* __restrict__ lhsp,    // 256 f32
        const float* __restrict__ rhsp,    // 256 f32
        const float* __restrict__ Wp,      // 3072 f32
        const float* __restrict__ bptr,
        float* __restrict__ out) {
    __shared__ __align__(16) float prm[PRM_TOT];   // W | rhs | lhs (14.3 KB)
    __shared__ float tmp[1536];                    // [ch][R(32)][j(16)]
    __shared__ __align__(16) float weff[768];      // [ch][i(16)][j(16)]
    __shared__ int flag;

    const int tid  = threadIdx.x;
    const int lane = tid & 63;
    const int w    = tid >> 6;
    const int wrow = blockIdx.x * ROWS_PER_BLOCK + w * 8;   // 8 rows per wave

    if (tid == 0) flag = 0;
    __syncthreads();            // nothing in flight -> free drain

    // ---- producer issues param loads FIRST (oldest in its vmcnt queue) ----
    if (w == 0) {
        #pragma unroll
        for (int c = 0; c < 12; ++c)
            async_lds16(Wp + c * 256 + lane * 4, prm + PRM_W + c * 256);
        async_lds16(rhsp + lane * 4, prm + PRM_RHS);
        async_lds16(lhsp + lane * 4, prm + PRM_LHS);
    }
    __builtin_amdgcn_sched_barrier(0);

    // ---- all waves: issue 12 x float4 (rows +0..+3) ----
    const float4* xr = x4 + (size_t)wrow * ROW_F4 + lane;
    float4 xa[2][3], xb[2][3];
    #pragma unroll
    for (int r = 0; r < 2; ++r)
        #pragma unroll
        for (int k = 0; k < 3; ++k)
            xa[r][k] = xr[r * ROW_F4 + k * 64];
    #pragma unroll
    for (int r = 0; r < 2; ++r)
        #pragma unroll
        for (int k = 0; k < 3; ++k)
            xb[r][k] = xr[(2 + r) * ROW_F4 + k * 64];
    __builtin_amdgcn_sched_barrier(0);     // pin all issues above this point

    volatile int* vflag = &flag;
    const int g = lane >> 4;               // 0..3
    const int j = lane & 15;               // preserved column -> tmp is lane-private

    if (w == 0) {
        // ================= producer: weff contraction (one wave) ===========
        const float4* rhv = (const float4*)(prm + PRM_RHS);
        const float4* Wlv = (const float4*)(prm + PRM_W);
        const float*  lh  = prm + PRM_LHS;
        const int c_ = j >> 3, q = j & 7;

        // rhs row for this lane's fixed j (4 float4, reused 24x)
        const float4 rr0 = rhv[c_ * 32 + q * 4 + 0];
        const float4 rr1 = rhv[c_ * 32 + q * 4 + 1];
        const float4 rr2 = rhv[c_ * 32 + q * 4 + 2];
        const float4 rr3 = rhv[c_ * 32 + q * 4 + 3];

        // stage A: tmp[v*16 + j], v = ch*32+R = g + 4s  (lane-private column j)
        #pragma unroll
        for (int s = 0; s < 24; ++s) {
            int v  = g + 4 * s;            // 0..95
            int ch = v >> 5, R = v & 31;
            const float4* wp = Wlv + ch * 256 + R * 8 + c_ * 4;
            tmp[v * 16 + j] = dot4(rr0, wp[0]) + dot4(rr1, wp[1])
                            + dot4(rr2, wp[2]) + dot4(rr3, wp[3]);
        }

        // stage B: weff[ch*256 + i*16 + j], i = g + 4*ii (reads own column j)
        #pragma unroll
        for (int ii = 0; ii < 4; ++ii) {
            int i = g + 4 * ii;            // 0..15
            int r = i >> 3, p = i & 7;
            float lv[16];
            #pragma unroll
            for (int P = 0; P < 16; ++P) lv[P] = lh[r * 128 + P * 8 + p];
            #pragma unroll
            for (int ch = 0; ch < 3; ++ch) {
                const float* tp = tmp + ch * 512 + r * 256 + j;
                float acc = 0.f;
                #pragma unroll
                for (int P = 0; P < 16; ++P) acc += lv[P] * tp[P * 16];
                weff[ch * 256 + i * 16 + j] = acc;
            }
        }
        __threadfence_block();             // weff visible before flag
        if (lane == 0) *vflag = 1;
    } else {
        // ================= consumers: wait for weff ========================
        while (*vflag == 0) { }
        __threadfence_block();             // acquire: no weff read before flag
    }

    // ---- per-lane weight fragment (LDS) + bias ----
    const float4* wv4 = (const float4*)weff;
    const float4 wv0 = wv4[lane];
    const float4 wv1 = wv4[lane + 64];
    const float4 wv2 = wv4[lane + 128];
    const float  bias = bptr[0];

    // ---- barrier-free pipelined streaming: 4 iters x 2 rows, depth-2 ----
    {   // t=0: consume rows 0,1 ; reload xa <- rows 4,5
        float a0 = dot4(xa[0][0], wv0) + dot4(xa[0][1], wv1) + dot4(xa[0][2], wv2);
        float a1 = dot4(xa[1][0], wv0) + dot4(xa[1][1], wv1) + dot4(xa[1][2], wv2);
        #pragma unroll
        for (int r = 0; r < 2; ++r)
            #pragma unroll
            for (int k = 0; k < 3; ++k)
                xa[r][k] = xr[(4 + r) * ROW_F4 + k * 64];
        reduce2_store(a0, a1, lane, out + wrow, bias);
    }
    {   // t=1: consume rows 2,3 ; reload xb <- rows 6,7
        float a0 = dot4(xb[0][0], wv0) + dot4(xb[0][1], wv1) + dot4(xb[0][2], wv2);
        float a1 = dot4(xb[1][0], wv0) + dot4(xb[1][1], wv1) + dot4(xb[1][2], wv2);
        #pragma unroll
        for (int r = 0; r < 2; ++r)
            #pragma unroll
            for (int k = 0; k < 3; ++k)
                xb[r][k] = xr[(6 + r) * ROW_F4 + k * 64];
        reduce2_store(a0, a1, lane, out + wrow + 2, bias);
    }
    {   // t=2: consume rows 4,5
        float a0 = dot4(xa[0][0], wv0) + dot4(xa[0][1], wv1) + dot4(xa[0][2], wv2);
        float a1 = dot4(xa[1][0], wv0) + dot4(xa[1][1], wv1) + dot4(xa[1][2], wv2);
        reduce2_store(a0, a1, lane, out + wrow + 4, bias);
    }
    {   // t=3: consume rows 6,7
        float a0 = dot4(xb[0][0], wv0) + dot4(xb[0][1], wv1) + dot4(xb[0][2], wv2);
        float a1 = dot4(xb[1][0], wv0) + dot4(xb[1][1], wv1) + dot4(xb[1][2], wv2);
        reduce2_store(a0, a1, lane, out + wrow + 6, bias);
    }
}

extern "C" void kernel_launch(void* const* d_in, const int* in_sizes, int n_in,
                              void* d_out, int out_size, void* d_ws, size_t ws_size,
                              hipStream_t stream) {
    const float* x   = (const float*)d_in[0];   // [32768, 3, 16, 16]
    const float* lhs = (const float*)d_in[1];   // [2, 16, 8]
    const float* rhs = (const float*)d_in[2];   // [2, 8, 16]
    const float* W   = (const float*)d_in[3];   // [1, 3072]
    const float* b   = (const float*)d_in[4];   // [1]
    float* out = (float*)d_out;                 // [32768]

    fused_pc_kernel<<<GRID_BLOCKS, 256, 0, stream>>>(
        (const float4*)x, lhs, rhs, W, b, out);
}

// Round 9
// 26.292 us; speedup vs baseline: 1.0184x; 1.0184x over previous
//
#include <hip/hip_runtime.h>
#include <hip/hip_bf16.h>

// x: [32768, 3, 16, 16] f32 ; lhs: [2, 16, 8] ; rhs: [2, 8, 16] ; W: [1, 3072] ; b: [1]
// out: [32768] f32
//
// Algebraic collapse (verified R1-R8, absmax <= 1e-3):
//   out[b] = dot(x[b] (768 f32), Weff (768 f32)) + bias
//   Weff[ch, r*8+p, c*8+q] = sum_{P,Q} lhs[r,P,p] * rhs[c,q,Q]
//                            * W[ch*1024 + (r*16+P)*32 + (c*16+Q)]
//
// R9: R7 base (1024 blocks, 32 rows/block, 4-wave contraction) with a
// stage-interleaved x-issue schedule. hipcc drains vmcnt(0) at every
// s_barrier (m97; confirmed R6 null) - so instead of fighting the drains,
// make every drain PRODUCTIVE: rows 0-3 in flight at B1, rows 4-5 issued
// after B1 and in flight during stage A (drained at B2), rows 6-7 issued
// after B2 and in flight during stage B (drained at B3). HBM demand is
// continuous; the R7 contraction bubble (~1.3us of idle HBM) disappears.

#define BATCH 32768
#define ROW_F4 192              // 768 floats per sample in float4 units
#define ROWS_PER_BLOCK 32
#define GRID_BLOCKS (BATCH / ROWS_PER_BLOCK)   // 1024 = 4 blocks/CU, 1 generation

__device__ __forceinline__ float dot4(const float4& a, const float4& b) {
    return a.x * b.x + a.y * b.y + a.z * b.z + a.w * b.w;
}

// Merged 2-row wave64 reduction: 6 shfl; lanes 0/1 store rows 0/1.
__device__ __forceinline__ void reduce2_store(float a0, float a1, int lane,
                                              float* __restrict__ outp,
                                              float bias) {
    a0 += __shfl_xor(a0, 1);
    a1 += __shfl_xor(a1, 1);
    float b = (lane & 1) ? a1 : a0;
    b += __shfl_xor(b, 2);
    b += __shfl_xor(b, 4);
    b += __shfl_xor(b, 8);
    b += __shfl_xor(b, 16);
    b += __shfl_xor(b, 32);
    if (lane < 2) outp[lane] = b + bias;
}

__global__ __launch_bounds__(256, 4) void fused_compressor_kernel(
        const float4* __restrict__ x4,
        const float4* __restrict__ lhs4,   // 64 float4
        const float4* __restrict__ rhs4,   // 64 float4
        const float4* __restrict__ W4,     // 768 float4
        const float* __restrict__ bptr,
        float* __restrict__ out) {
    __shared__ __align__(16) float Wl[3072];    // W copy (12 KB)
    __shared__ __align__(16) float rh[256];     // rhs copy
    __shared__ __align__(16) float lh[256];     // lhs copy
    __shared__ float tmp[1536];                 // [ch][R(32)][j(16)]
    __shared__ __align__(16) float weff[768];   // [ch][i(16)][j(16)]

    const int tid  = threadIdx.x;
    const int lane = tid & 63;
    const int w    = tid >> 6;
    const int wrow = blockIdx.x * ROWS_PER_BLOCK + w * 8;   // 8 rows per wave

    const float4* xr = x4 + (size_t)wrow * ROW_F4 + lane;

    // ---- prologue: params + rows 0-3 (in flight at B1; drain productive) ----
    float4 wreg0 = W4[tid];
    float4 wreg1 = W4[tid + 256];
    float4 wreg2 = W4[tid + 512];
    int sidx = tid & 127;
    float4 sreg = (sidx < 64) ? rhs4[sidx] : lhs4[sidx - 64];

    float4 xa[2][3], xb[2][3];
    #pragma unroll
    for (int r = 0; r < 2; ++r)
        #pragma unroll
        for (int k = 0; k < 3; ++k)
            xa[r][k] = xr[r * ROW_F4 + k * 64];            // rows 0,1
    #pragma unroll
    for (int r = 0; r < 2; ++r)
        #pragma unroll
        for (int k = 0; k < 3; ++k)
            xb[r][k] = xr[(2 + r) * ROW_F4 + k * 64];      // rows 2,3

    reinterpret_cast<float4*>(Wl)[tid]       = wreg0;
    reinterpret_cast<float4*>(Wl)[tid + 256] = wreg1;
    reinterpret_cast<float4*>(Wl)[tid + 512] = wreg2;
    if (tid < 128) {
        if (tid < 64) reinterpret_cast<float4*>(rh)[tid] = sreg;
        else          reinterpret_cast<float4*>(lh)[tid - 64] = sreg;
    }
    __syncthreads();   // B1: drains prologue (productive HBM wait)

    // ---- issue rows 4,5 now: in flight during stage A, drained at B2 ----
    float4 xc[2][3];
    #pragma unroll
    for (int r = 0; r < 2; ++r)
        #pragma unroll
        for (int k = 0; k < 3; ++k)
            xc[r][k] = xr[(4 + r) * ROW_F4 + k * 64];
    __builtin_amdgcn_sched_barrier(0);   // pin issues above stage A

    // ---- stage A (LDS): tmp[ch,R,j] = sum_Q rhs[c,q,Q]*W[ch,R,c*16+Q] ----
    const float4* rhv = reinterpret_cast<const float4*>(rh);
    const float4* Wlv = reinterpret_cast<const float4*>(Wl);
    #pragma unroll
    for (int s = 0; s < 6; ++s) {
        int idx = tid + (s << 8);           // 0..1535
        int ch  = idx >> 9;
        int rem = idx & 511;
        int R   = rem >> 4;
        int j   = rem & 15;
        int c   = j >> 3;
        int q   = j & 7;
        const float4* rp = rhv + c * 32 + q * 4;             // 16 floats
        const float4* wp = Wlv + ch * 256 + R * 8 + c * 4;   // 16 floats
        tmp[idx] = dot4(rp[0], wp[0]) + dot4(rp[1], wp[1])
                 + dot4(rp[2], wp[2]) + dot4(rp[3], wp[3]);
    }
    __syncthreads();   // B2: drains rows 4,5 (productive HBM wait)

    // ---- issue rows 6,7 now: in flight during stage B, drained at B3 ----
    float4 xd[2][3];
    #pragma unroll
    for (int r = 0; r < 2; ++r)
        #pragma unroll
        for (int k = 0; k < 3; ++k)
            xd[r][k] = xr[(6 + r) * ROW_F4 + k * 64];
    __builtin_amdgcn_sched_barrier(0);   // pin issues above stage B

    // ---- stage B (LDS): weff[ch,i,j] = sum_P lhs[r,P,p]*tmp[ch,r*16+P,j] ----
    #pragma unroll
    for (int s = 0; s < 3; ++s) {
        int idx = tid + (s << 8);           // 0..767
        int ch  = idx >> 8;
        int rem = idx & 255;
        int i   = rem >> 4;
        int j   = rem & 15;
        int r   = i >> 3;
        int p   = i & 7;
        const float* lp = lh + r * 128 + p;
        const float* tp = tmp + ch * 512 + r * 256 + j;
        float acc = 0.f;
        #pragma unroll
        for (int P = 0; P < 16; ++P) acc += lp[P * 8] * tp[P * 16];
        weff[idx] = acc;
    }
    __syncthreads();   // B3: drains rows 6,7 (productive HBM wait)

    // ---- per-lane weight fragment (LDS) + bias ----
    const float4* wv4 = reinterpret_cast<const float4*>(weff);
    const float4 wv0 = wv4[lane];
    const float4 wv1 = wv4[lane + 64];
    const float4 wv2 = wv4[lane + 128];
    const float  bias = bptr[0];

    // ---- consume all 8 rows from registers (no loads; short VALU tail) ----
    {
        float a0 = dot4(xa[0][0], wv0) + dot4(xa[0][1], wv1) + dot4(xa[0][2], wv2);
        float a1 = dot4(xa[1][0], wv0) + dot4(xa[1][1], wv1) + dot4(xa[1][2], wv2);
        reduce2_store(a0, a1, lane, out + wrow, bias);
    }
    {
        float a0 = dot4(xb[0][0], wv0) + dot4(xb[0][1], wv1) + dot4(xb[0][2], wv2);
        float a1 = dot4(xb[1][0], wv0) + dot4(xb[1][1], wv1) + dot4(xb[1][2], wv2);
        reduce2_store(a0, a1, lane, out + wrow + 2, bias);
    }
    {
        float a0 = dot4(xc[0][0], wv0) + dot4(xc[0][1], wv1) + dot4(xc[0][2], wv2);
        float a1 = dot4(xc[1][0], wv0) + dot4(xc[1][1], wv1) + dot4(xc[1][2], wv2);
        reduce2_store(a0, a1, lane, out + wrow + 4, bias);
    }
    {
        float a0 = dot4(xd[0][0], wv0) + dot4(xd[0][1], wv1) + dot4(xd[0][2], wv2);
        float a1 = dot4(xd[1][0], wv0) + dot4(xd[1][1], wv1) + dot4(xd[1][2], wv2);
        reduce2_store(a0, a1, lane, out + wrow + 6, bias);
    }
}

extern "C" void kernel_launch(void* const* d_in, const int* in_sizes, int n_in,
                              void* d_out, int out_size, void* d_ws, size_t ws_size,
                              hipStream_t stream) {
    const float* x   = (const float*)d_in[0];   // [32768, 3, 16, 16]
    const float* lhs = (const float*)d_in[1];   // [2, 16, 8]
    const float* rhs = (const float*)d_in[2];   // [2, 8, 16]
    const float* W   = (const float*)d_in[3];   // [1, 3072]
    const float* b   = (const float*)d_in[4];   // [1]
    float* out = (float*)d_out;                 // [32768]

    fused_compressor_kernel<<<GRID_BLOCKS, 256, 0, stream>>>(
        (const float4*)x, (const float4*)lhs, (const float4*)rhs,
        (const float4*)W, b, out);
}

// Round 10
// 20.631 us; speedup vs baseline: 1.2978x; 1.2744x over previous
//
#include <hip/hip_runtime.h>
#include <hip/hip_bf16.h>

// x: [32768, 3, 16, 16] f32 ; lhs: [2, 16, 8] ; rhs: [2, 8, 16] ; W: [1, 3072] ; b: [1]
// out: [32768] f32
//
// Algebraic collapse (verified R1-R9, absmax <= 1e-3):
//   out[b] = dot(x[b] (768 f32), Weff (768 f32)) + bias
//   Weff[ch, r*8+p, c*8+q] = sum_{P,Q} lhs[r,P,p] * rhs[c,q,Q]
//                            * W[ch*1024 + (r*16+P)*32 + (c*16+Q)]
//
// R10: R7 structure (1024 blocks, 32 rows/block, 4-wave contraction,
// depth-2 pipelined consume) with every s_barrier replaced by an LDS
// wave-counting software barrier. hipcc emits s_waitcnt vmcnt(0) before
// s_barrier (m97; R6 null confirmed), which drained the x prefetch and
// exposed the ~2us contraction as an HBM bubble. The software barrier
// syncs LDS (lgkmcnt only) -> the 12 x float4/wave issued in the
// prologue stay IN FLIGHT through the whole weff contraction.

#define BATCH 32768
#define ROW_F4 192              // 768 floats per sample in float4 units
#define ROWS_PER_BLOCK 32
#define GRID_BLOCKS (BATCH / ROWS_PER_BLOCK)   // 1024 = 4 blocks/CU, 1 generation
#define NWAVES 4

__device__ __forceinline__ float dot4(const float4& a, const float4& b) {
    return a.x * b.x + a.y * b.y + a.z * b.z + a.w * b.w;
}

// Wave-counting LDS barrier: orders LDS writes -> LDS reads across waves
// WITHOUT touching vmcnt (x global loads stay outstanding).
__device__ __forceinline__ void swbar(int* ctr, int lane, int target) {
    asm volatile("s_waitcnt lgkmcnt(0)" ::: "memory");  // my ds_writes landed
    if (lane == 0) atomicAdd(ctr, 1);
    while (*(volatile int*)ctr < target) { }
    asm volatile("" ::: "memory");                      // no hoisting past spin
    __builtin_amdgcn_sched_barrier(0);
}

// Merged 2-row wave64 reduction: 6 shfl; lanes 0/1 store rows 0/1.
__device__ __forceinline__ void reduce2_store(float a0, float a1, int lane,
                                              float* __restrict__ outp,
                                              float bias) {
    a0 += __shfl_xor(a0, 1);
    a1 += __shfl_xor(a1, 1);
    float b = (lane & 1) ? a1 : a0;
    b += __shfl_xor(b, 2);
    b += __shfl_xor(b, 4);
    b += __shfl_xor(b, 8);
    b += __shfl_xor(b, 16);
    b += __shfl_xor(b, 32);
    if (lane < 2) outp[lane] = b + bias;
}

__global__ __launch_bounds__(256, 4) void fused_compressor_kernel(
        const float4* __restrict__ x4,
        const float4* __restrict__ lhs4,   // 64 float4
        const float4* __restrict__ rhs4,   // 64 float4
        const float4* __restrict__ W4,     // 768 float4
        const float* __restrict__ bptr,
        float* __restrict__ out) {
    __shared__ __align__(16) float Wl[3072];    // W copy (12 KB)
    __shared__ __align__(16) float rh[256];     // rhs copy
    __shared__ __align__(16) float lh[256];     // lhs copy
    __shared__ float tmp[1536];                 // [ch][R(32)][j(16)]
    __shared__ __align__(16) float weff[768];   // [ch][i(16)][j(16)]
    __shared__ int bar1, bar2, bar3;

    const int tid  = threadIdx.x;
    const int lane = tid & 63;
    const int w    = tid >> 6;
    const int wrow = blockIdx.x * ROWS_PER_BLOCK + w * 8;   // 8 rows per wave

    if (tid == 0) { bar1 = 0; bar2 = 0; bar3 = 0; }
    __syncthreads();                    // nothing outstanding -> free drain

    // ---- 1) param loads FIRST (oldest in vmcnt queue) ----
    float4 wreg0 = W4[tid];
    float4 wreg1 = W4[tid + 256];
    float4 wreg2 = W4[tid + 512];
    int sidx = tid & 127;
    float4 sreg = (sidx < 64) ? rhs4[sidx] : lhs4[sidx - 64];
    __builtin_amdgcn_sched_barrier(0);

    // ---- 2) x prefetch: rows 0-3 (12 float4/lane); stays in flight
    //         through the contraction (no vmcnt(0) anywhere below) ----
    const float4* xr = x4 + (size_t)wrow * ROW_F4 + lane;
    float4 xa[2][3], xb[2][3];
    #pragma unroll
    for (int r = 0; r < 2; ++r)
        #pragma unroll
        for (int k = 0; k < 3; ++k)
            xa[r][k] = xr[r * ROW_F4 + k * 64];            // rows 0,1
    #pragma unroll
    for (int r = 0; r < 2; ++r)
        #pragma unroll
        for (int k = 0; k < 3; ++k)
            xb[r][k] = xr[(2 + r) * ROW_F4 + k * 64];      // rows 2,3
    __builtin_amdgcn_sched_barrier(0);

    // ---- 3) stage params to LDS (waits vmcnt<=12: x stays in flight) ----
    reinterpret_cast<float4*>(Wl)[tid]       = wreg0;
    reinterpret_cast<float4*>(Wl)[tid + 256] = wreg1;
    reinterpret_cast<float4*>(Wl)[tid + 512] = wreg2;
    if (tid < 128) {
        if (tid < 64) reinterpret_cast<float4*>(rh)[tid] = sreg;
        else          reinterpret_cast<float4*>(lh)[tid - 64] = sreg;
    }
    swbar(&bar1, lane, NWAVES);

    // ---- stage A (LDS): tmp[ch,R,j] = sum_Q rhs[c,q,Q]*W[ch,R,c*16+Q] ----
    const float4* rhv = reinterpret_cast<const float4*>(rh);
    const float4* Wlv = reinterpret_cast<const float4*>(Wl);
    #pragma unroll
    for (int s = 0; s < 6; ++s) {
        int idx = tid + (s << 8);           // 0..1535
        int ch  = idx >> 9;
        int rem = idx & 511;
        int R   = rem >> 4;
        int j   = rem & 15;
        int c   = j >> 3;
        int q   = j & 7;
        const float4* rp = rhv + c * 32 + q * 4;             // 16 floats
        const float4* wp = Wlv + ch * 256 + R * 8 + c * 4;   // 16 floats
        tmp[idx] = dot4(rp[0], wp[0]) + dot4(rp[1], wp[1])
                 + dot4(rp[2], wp[2]) + dot4(rp[3], wp[3]);
    }
    swbar(&bar2, lane, NWAVES);

    // ---- stage B (LDS): weff[ch,i,j] = sum_P lhs[r,P,p]*tmp[ch,r*16+P,j] ----
    #pragma unroll
    for (int s = 0; s < 3; ++s) {
        int idx = tid + (s << 8);           // 0..767
        int ch  = idx >> 8;
        int rem = idx & 255;
        int i   = rem >> 4;
        int j   = rem & 15;
        int r   = i >> 3;
        int p   = i & 7;
        const float* lp = lh + r * 128 + p;
        const float* tp = tmp + ch * 512 + r * 256 + j;
        float acc = 0.f;
        #pragma unroll
        for (int P = 0; P < 16; ++P) acc += lp[P * 8] * tp[P * 16];
        weff[idx] = acc;
    }
    swbar(&bar3, lane, NWAVES);

    // ---- per-lane weight fragment (LDS) + bias ----
    const float4* wv4 = reinterpret_cast<const float4*>(weff);
    const float4 wv0 = wv4[lane];
    const float4 wv1 = wv4[lane + 64];
    const float4 wv2 = wv4[lane + 128];
    const float  bias = bptr[0];

    // ---- pipelined streaming loop: 4 iters x 2 rows, depth-2 prefetch ----
    {   // t=0: consume rows 0,1 (x drains here - productive); reload 4,5
        float a0 = dot4(xa[0][0], wv0) + dot4(xa[0][1], wv1) + dot4(xa[0][2], wv2);
        float a1 = dot4(xa[1][0], wv0) + dot4(xa[1][1], wv1) + dot4(xa[1][2], wv2);
        #pragma unroll
        for (int r = 0; r < 2; ++r)
            #pragma unroll
            for (int k = 0; k < 3; ++k)
                xa[r][k] = xr[(4 + r) * ROW_F4 + k * 64];
        reduce2_store(a0, a1, lane, out + wrow, bias);
    }
    {   // t=1: consume rows 2,3; reload 6,7
        float a0 = dot4(xb[0][0], wv0) + dot4(xb[0][1], wv1) + dot4(xb[0][2], wv2);
        float a1 = dot4(xb[1][0], wv0) + dot4(xb[1][1], wv1) + dot4(xb[1][2], wv2);
        #pragma unroll
        for (int r = 0; r < 2; ++r)
            #pragma unroll
            for (int k = 0; k < 3; ++k)
                xb[r][k] = xr[(6 + r) * ROW_F4 + k * 64];
        reduce2_store(a0, a1, lane, out + wrow + 2, bias);
    }
    {   // t=2: consume rows 4,5
        float a0 = dot4(xa[0][0], wv0) + dot4(xa[0][1], wv1) + dot4(xa[0][2], wv2);
        float a1 = dot4(xa[1][0], wv0) + dot4(xa[1][1], wv1) + dot4(xa[1][2], wv2);
        reduce2_store(a0, a1, lane, out + wrow + 4, bias);
    }
    {   // t=3: consume rows 6,7
        float a0 = dot4(xb[0][0], wv0) + dot4(xb[0][1], wv1) + dot4(xb[0][2], wv2);
        float a1 = dot4(xb[1][0], wv0) + dot4(xb[1][1], wv1) + dot4(xb[1][2], wv2);
        reduce2_store(a0, a1, lane, out + wrow + 6, bias);
    }
}

extern "C" void kernel_launch(void* const* d_in, const int* in_sizes, int n_in,
                              void* d_out, int out_size, void* d_ws, size_t ws_size,
                              hipStream_t stream) {
    const float* x   = (const float*)d_in[0];   // [32768, 3, 16, 16]
    const float* lhs = (const float*)d_in[1];   // [2, 16, 8]
    const float* rhs = (const float*)d_in[2];   // [2, 8, 16]
    const float* W   = (const float*)d_in[3];   // [1, 3072]
    const float* b   = (const float*)d_in[4];   // [1]
    float* out = (float*)d_out;                 // [32768]

    fused_compressor_kernel<<<GRID_BLOCKS, 256, 0, stream>>>(
        (const float4*)x, (const float4*)lhs, (const float4*)rhs,
        (const float4*)W, b, out);
}